// Round 3
// baseline (349.834 us; speedup 1.0000x reference)
//
#include <hip/hip_runtime.h>

#define N_NODES 100000
#define N_EDGES 1600000
#define ET (N_EDGES + N_NODES)
#define NEG_SLOPE 0.2f

// bucket sort params
#define BSHIFT 9
#define BW 512                                  // nodes per bucket
#define NBUCK ((N_NODES + BW - 1) / BW)         // 196
#define BCAP 10240
#define BINCH 2048                              // edges per bin block

typedef unsigned short u16;
typedef unsigned int u32;

__device__ __forceinline__ float bf2f(u16 v) {
    return __uint_as_float(((u32)v) << 16);
}
__device__ __forceinline__ u16 f2bf(float f) {
    u32 u = __float_as_uint(f);
    u32 r = (u + 0x7FFFu + ((u >> 16) & 1u)) >> 16;  // RNE
    return (u16)r;
}
__device__ __forceinline__ float lrelu(float x) { return x > 0.f ? x : NEG_SLOPE * x; }
__device__ __forceinline__ float ldf(const void* p, int i, int bf) {
    return bf ? bf2f(((const u16*)p)[i]) : ((const float*)p)[i];
}
__device__ __forceinline__ int get_dst(const int* __restrict__ ei, int e, int ei64) {
    if (e < N_EDGES) return ei64 ? ei[2 * (N_EDGES + e)] : ei[N_EDGES + e];
    return e - N_EDGES;
}
__device__ __forceinline__ int get_src(const int* __restrict__ ei, int e, int ei64) {
    if (e < N_EDGES) return ei64 ? ei[2 * e] : ei[e];
    return e - N_EDGES;
}

// ---------------------------------------------------------------------------
// Detect input storage + zero bcnt (memset dispatch folded in).
// ---------------------------------------------------------------------------
__global__ void detect_kernel(const u32* __restrict__ x32, const int* __restrict__ ei,
                              int* __restrict__ flags, int* __restrict__ bcnt) {
    int lane = threadIdx.x;  // 64
    for (int i = lane; i < 256; i += 64) bcnt[i] = 0;
    u32 e = (x32[lane] >> 7) & 0xFFu;
    int ok = (e >= 96u && e <= 143u) ? 1 : 0;
    int cnt = (int)__popcll(__ballot(ok));
    int nz = (ei[2 * lane + 1] != 0) + (ei[2 * (lane + 64) + 1] != 0);
    #pragma unroll
    for (int off = 32; off > 0; off >>= 1) nz += __shfl_xor(nz, off);
    if (lane == 0) { flags[0] = (cnt >= 48) ? 1 : 0; flags[1] = (nz == 0) ? 1 : 0; }
}

// ---------------------------------------------------------------------------
// Pass 1: bin edges by dst>>9 into 196 buckets; code = (dst&511)<<17 | src.
// ---------------------------------------------------------------------------
__global__ __launch_bounds__(256) void bin_kernel(
    const int* __restrict__ ei, const int* __restrict__ flags,
    int* __restrict__ bcnt, u32* __restrict__ bbuf)
{
    __shared__ int hist[NBUCK];
    const int t = threadIdx.x;
    const int base = blockIdx.x * BINCH;
    const int ei64 = flags[1];
    for (int i = t; i < NBUCK; i += 256) hist[i] = 0;
    __syncthreads();
    for (int i = t; i < BINCH; i += 256) {
        int e = base + i;
        if (e >= ET) break;
        int d = get_dst(ei, e, ei64);
        atomicAdd(&hist[d >> BSHIFT], 1);
    }
    __syncthreads();
    for (int i = t; i < NBUCK; i += 256) {
        int c = hist[i];
        hist[i] = (c > 0) ? atomicAdd(&bcnt[i], c) : 0;
    }
    __syncthreads();
    for (int i = t; i < BINCH; i += 256) {
        int e = base + i;
        if (e >= ET) break;
        int d = get_dst(ei, e, ei64);
        int s = get_src(ei, e, ei64);
        int b = d >> BSHIFT;
        int pos = atomicAdd(&hist[b], 1);
        if (pos < BCAP)
            bbuf[(size_t)b * BCAP + pos] = ((u32)(d & (BW - 1)) << 17) | (u32)s;
    }
}

// exclusive scan of clamped bucket counts -> bbase[NBUCK+1]
__global__ __launch_bounds__(256) void bscan_kernel(
    const int* __restrict__ bcnt, int* __restrict__ bbase)
{
    __shared__ int sd[256];
    int t = threadIdx.x;
    int v = (t < NBUCK) ? min(bcnt[t], BCAP) : 0;
    sd[t] = v;
    __syncthreads();
    for (int off = 1; off < 256; off <<= 1) {
        int x = (t >= off) ? sd[t - off] : 0;
        __syncthreads();
        sd[t] += x;
        __syncthreads();
    }
    if (t < NBUCK) bbase[t] = sd[t] - v;
    if (t == NBUCK - 1) bbase[NBUCK] = sd[t];
}

// ---------------------------------------------------------------------------
// Pass 2: one block (1024 threads) per bucket -> rowptr + dst-sorted ssrc.
// ---------------------------------------------------------------------------
__global__ __launch_bounds__(1024) void scatter_kernel(
    const int* __restrict__ bcnt, const int* __restrict__ bbase,
    const u32* __restrict__ bbuf, int* __restrict__ rowptr, int* __restrict__ ssrc)
{
    __shared__ int hist[BW];
    __shared__ int cur[BW];
    __shared__ int wtot[4];
    __shared__ int lds_s[BCAP];
    const int t = threadIdx.x;
    const int b = blockIdx.x;
    const int cnt = min(bcnt[b], BCAP);
    const int base = bbase[b];
    const u32* mybuf = bbuf + (size_t)b * BCAP;

    if (t < BW) hist[t] = 0;
    __syncthreads();
    for (int i = t; i < cnt; i += 1024) atomicAdd(&hist[(int)(mybuf[i] >> 17)], 1);
    __syncthreads();
    int a0 = 0, a1 = 0, s = 0, v = 0;
    const int lane = t & 63, wid = t >> 6;
    if (t < 256) {
        a0 = hist[2 * t]; a1 = hist[2 * t + 1];
        s = a0 + a1;
        v = s;
        #pragma unroll
        for (int off = 1; off < 64; off <<= 1) {
            int n = __shfl_up(v, off);
            if (lane >= off) v += n;
        }
        if (lane == 63) wtot[wid] = v;
    }
    __syncthreads();
    if (t == 0) {
        int acc = 0;
        #pragma unroll
        for (int w = 0; w < 4; ++w) { int tmp = wtot[w]; wtot[w] = acc; acc += tmp; }
    }
    __syncthreads();
    if (t < 256) {
        int excl = v + wtot[wid] - s;
        cur[2 * t] = excl;
        cur[2 * t + 1] = excl + a0;
    }
    __syncthreads();
    if (t < BW) {
        int g = b * BW + t;
        if (g < N_NODES) rowptr[g] = base + cur[t];
    }
    if (b == NBUCK - 1 && t == 0) rowptr[N_NODES] = bbase[NBUCK];
    __syncthreads();
    for (int i = t; i < cnt; i += 1024) {
        u32 code = mybuf[i];
        int pos = atomicAdd(&cur[(int)(code >> 17)], 1);
        lds_s[pos] = (int)(code & 0x1FFFFu);
    }
    __syncthreads();
    for (int i = t; i < cnt; i += 1024) ssrc[base + i] = lds_s[i];
}

// ---------------------------------------------------------------------------
// GEMM1: h[N,64](bf16) = x[N,128] @ W[128,64]; as_/ad_ score dots.
// ---------------------------------------------------------------------------
__global__ __launch_bounds__(256) void gemm1_kernel(
    const float* __restrict__ x, const float* __restrict__ W,
    const void* __restrict__ a_src, const void* __restrict__ a_dst,
    const int* __restrict__ flags,
    u16* __restrict__ h, float* __restrict__ as_, float* __restrict__ ad_)
{
    __shared__ float xs[256 * 33];   // 33.8 KB
    __shared__ float Wl[32 * 64];    // 8 KB
    const int t = threadIdx.x;
    const int node0 = blockIdx.x * 256;
    const int bf = flags[0];
    const int ng = t >> 3;
    const int cg = t & 7;

    float acc[8][8];
    #pragma unroll
    for (int i = 0; i < 8; ++i)
        #pragma unroll
        for (int j = 0; j < 8; ++j) acc[i][j] = 0.f;

    for (int kc = 0; kc < 4; ++kc) {
        const int kb = kc * 32;
        const int c4 = t & 7;
        #pragma unroll
        for (int p = 0; p < 8; ++p) {
            int row = (t >> 3) + p * 32;
            int n = node0 + row;
            float4 vv = make_float4(0.f, 0.f, 0.f, 0.f);
            if (n < N_NODES) {
                if (!bf) {
                    vv = *(const float4*)(x + (size_t)n * 128 + kb + c4 * 4);
                } else {
                    const u16* xh = (const u16*)x;
                    vv.x = bf2f(xh[(size_t)n * 128 + kb + c4 * 4 + 0]);
                    vv.y = bf2f(xh[(size_t)n * 128 + kb + c4 * 4 + 1]);
                    vv.z = bf2f(xh[(size_t)n * 128 + kb + c4 * 4 + 2]);
                    vv.w = bf2f(xh[(size_t)n * 128 + kb + c4 * 4 + 3]);
                }
            }
            float* dstp = &xs[row * 33 + c4 * 4];
            dstp[0] = vv.x; dstp[1] = vv.y; dstp[2] = vv.z; dstp[3] = vv.w;
        }
        if (!bf) {
            #pragma unroll
            for (int qq = 0; qq < 2; ++qq) {
                int f4 = t * 2 + qq;
                ((float4*)Wl)[f4] = ((const float4*)(W + (size_t)kb * 64))[f4];
            }
        } else {
            const u16* Wh = (const u16*)W;
            for (int i = t; i < 2048; i += 256) Wl[i] = bf2f(Wh[(size_t)kb * 64 + i]);
        }
        __syncthreads();

        for (int kk = 0; kk < 32; ++kk) {
            float xr[8];
            #pragma unroll
            for (int i = 0; i < 8; ++i) xr[i] = xs[(ng * 8 + i) * 33 + kk];
            float4 w0 = *(const float4*)&Wl[kk * 64 + cg * 8];
            float4 w1 = *(const float4*)&Wl[kk * 64 + cg * 8 + 4];
            const float wr[8] = {w0.x, w0.y, w0.z, w0.w, w1.x, w1.y, w1.z, w1.w};
            #pragma unroll
            for (int i = 0; i < 8; ++i)
                #pragma unroll
                for (int j = 0; j < 8; ++j)
                    acc[i][j] = fmaf(xr[i], wr[j], acc[i][j]);
        }
        __syncthreads();
    }

    float av[8], dv[8];
    #pragma unroll
    for (int j = 0; j < 8; ++j) {
        av[j] = ldf(a_src, cg * 8 + j, bf);
        dv[j] = ldf(a_dst, cg * 8 + j, bf);
    }
    #pragma unroll
    for (int i = 0; i < 8; ++i) {
        int n = node0 + ng * 8 + i;
        float ps = 0.f, pd = 0.f;
        #pragma unroll
        for (int j = 0; j < 8; ++j) { ps += acc[i][j] * av[j]; pd += acc[i][j] * dv[j]; }
        #pragma unroll
        for (int off = 1; off < 8; off <<= 1) {
            ps += __shfl_xor(ps, off);
            pd += __shfl_xor(pd, off);
        }
        if (n < N_NODES) {
            uint4 hv;
            hv.x = (u32)f2bf(acc[i][0]) | ((u32)f2bf(acc[i][1]) << 16);
            hv.y = (u32)f2bf(acc[i][2]) | ((u32)f2bf(acc[i][3]) << 16);
            hv.z = (u32)f2bf(acc[i][4]) | ((u32)f2bf(acc[i][5]) << 16);
            hv.w = (u32)f2bf(acc[i][6]) | ((u32)f2bf(acc[i][7]) << 16);
            *(uint4*)&h[(size_t)n * 64 + cg * 8] = hv;
            if (cg == 0) { as_[n] = ps; ad_[n] = pd; }
        }
    }
}

// ---------------------------------------------------------------------------
// Layer-1 aggregation, C=64. One wave per dst. r3: quarter-split uint2 gather
// (4 edges/group, 16 lanes/edge, 8 B/lane) with BATCHED issue: up to 8 groups'
// pair-table ds_reads + global loads in flight before any FMA (the old
// per-iteration ds_read->load->fma chain exposed ~800 cy per 2 edges; the
// kernel was latency-bound: VALU 43%, HBM 38%, occupancy 74%).
// Tail needs no masking: pair entries >= cnt have ex=0, sj=0 (reads h[0]).
// ---------------------------------------------------------------------------
__global__ __launch_bounds__(256) void gat_agg64_kernel(
    const int* __restrict__ rowptr, const int* __restrict__ ssrc,
    const float* __restrict__ as_, const float* __restrict__ ad_,
    const u16* __restrict__ h, float* __restrict__ agg)
{
    __shared__ uint2 pr[4][64];      // per-wave {ex_bits, sj<<7} pair table
    const int lane = threadIdx.x & 63;
    const int wid = threadIdx.x >> 6;
    const int dst = blockIdx.x * 4 + wid;
    if (dst >= N_NODES) return;
    uint2* pairs = pr[wid];
    const int beg = rowptr[dst], end = rowptr[dst + 1];
    const float add = ad_[dst];
    const int q = lane >> 4;                      // edge within group of 4
    const int i16 = lane & 15;                    // uint2 index within 128-B row
    const char* __restrict__ hb = (const char*)h; // byte base of h
    const u32 boff = (u32)(i16 * 8);

    float m = -1e30f, l = 0.f;
    float acc[4] = {0.f, 0.f, 0.f, 0.f};
    for (int base = beg; base < end; base += 64) {
        int j = base + lane;
        int sj = 0;
        float sc = -1e30f;
        if (j < end) { sj = ssrc[j]; sc = lrelu(as_[sj] + add); }
        float cm = sc;
        #pragma unroll
        for (int off = 32; off > 0; off >>= 1) cm = fmaxf(cm, __shfl_xor(cm, off));
        float nm = fmaxf(m, cm);
        float scale = __expf(m - nm);
        float ex = (j < end) ? __expf(sc - nm) : 0.f;
        float cs = ex;
        #pragma unroll
        for (int off = 32; off > 0; off >>= 1) cs += __shfl_xor(cs, off);
        l = l * scale + cs;
        #pragma unroll
        for (int c = 0; c < 4; ++c) acc[c] *= scale;
        m = nm;

        // publish {weight, row byte-offset} for this 64-edge block
        pairs[lane] = make_uint2(__float_as_uint(ex), ((u32)sj) << 7);
        __builtin_amdgcn_wave_barrier();
        asm volatile("s_waitcnt lgkmcnt(0)" ::: "memory");

        const int cnt = min(64, end - base);
        const int ngrp = (cnt + 3) >> 2;          // 4-edge groups, <= 16

        {   // batch 1: groups 0..7 (covers deg <= 32, the common case)
            const int nb = min(ngrp, 8);
            uint2 pv[8], qv[8];
            #pragma unroll
            for (int k = 0; k < 8; ++k) if (k < nb) pv[k] = pairs[(k << 2) + q];
            #pragma unroll
            for (int k = 0; k < 8; ++k) if (k < nb)
                qv[k] = *(const uint2*)(hb + (size_t)(pv[k].y + boff));
            #pragma unroll
            for (int k = 0; k < 8; ++k) if (k < nb) {
                float w = __uint_as_float(pv[k].x);
                acc[0] = fmaf(w, __uint_as_float(qv[k].x << 16), acc[0]);
                acc[1] = fmaf(w, __uint_as_float(qv[k].x & 0xFFFF0000u), acc[1]);
                acc[2] = fmaf(w, __uint_as_float(qv[k].y << 16), acc[2]);
                acc[3] = fmaf(w, __uint_as_float(qv[k].y & 0xFFFF0000u), acc[3]);
            }
        }
        if (ngrp > 8) {   // batch 2: groups 8..15
            const int nb = ngrp - 8;
            uint2 pv[8], qv[8];
            #pragma unroll
            for (int k = 0; k < 8; ++k) if (k < nb) pv[k] = pairs[((k + 8) << 2) + q];
            #pragma unroll
            for (int k = 0; k < 8; ++k) if (k < nb)
                qv[k] = *(const uint2*)(hb + (size_t)(pv[k].y + boff));
            #pragma unroll
            for (int k = 0; k < 8; ++k) if (k < nb) {
                float w = __uint_as_float(pv[k].x);
                acc[0] = fmaf(w, __uint_as_float(qv[k].x << 16), acc[0]);
                acc[1] = fmaf(w, __uint_as_float(qv[k].x & 0xFFFF0000u), acc[1]);
                acc[2] = fmaf(w, __uint_as_float(qv[k].y << 16), acc[2]);
                acc[3] = fmaf(w, __uint_as_float(qv[k].y & 0xFFFF0000u), acc[3]);
            }
        }
        __builtin_amdgcn_wave_barrier();   // keep reads before next block's write
    }
    #pragma unroll
    for (int c = 0; c < 4; ++c) {
        acc[c] += __shfl_xor(acc[c], 16);
        acc[c] += __shfl_xor(acc[c], 32);
    }
    if (q == 0) {
        float inv = 1.f / l;
        *(float4*)&agg[(size_t)dst * 64 + i16 * 4] =
            make_float4(acc[0] * inv, acc[1] * inv, acc[2] * inv, acc[3] * inv);
    }
}

// ---------------------------------------------------------------------------
// Layer-2 aggregation, C=32. r3: 8-edge groups (8 lanes/edge, uint2 loads),
// single batched issue (deg<=64 -> <=8 groups: ONE latency exposure per
// 64-edge block). Fused bias + log_softmax over 8 lanes x 4 channels.
// ---------------------------------------------------------------------------
__global__ __launch_bounds__(256) void gat_agg32_lsm_kernel(
    const int* __restrict__ rowptr, const int* __restrict__ ssrc,
    const float* __restrict__ as_, const float* __restrict__ ad_,
    const u16* __restrict__ h, const void* __restrict__ b2,
    const int* __restrict__ flags, float* __restrict__ out)
{
    __shared__ uint2 pr[4][64];      // per-wave {ex_bits, sj<<6} pair table
    const int lane = threadIdx.x & 63;
    const int wid = threadIdx.x >> 6;
    const int dst = blockIdx.x * 4 + wid;
    if (dst >= N_NODES) return;
    uint2* pairs = pr[wid];
    const int beg = rowptr[dst], end = rowptr[dst + 1];
    const float add = ad_[dst];
    const int e8 = lane >> 3;         // edge within group of 8
    const int i8 = lane & 7;          // uint2 index within 64-B row
    const int bf = flags[0];
    const char* __restrict__ hb = (const char*)h;
    const u32 boff = (u32)(i8 * 8);

    float m = -1e30f, l = 0.f;
    float acc[4] = {0.f, 0.f, 0.f, 0.f};
    for (int base = beg; base < end; base += 64) {
        int j = base + lane;
        int sj = 0;
        float sc = -1e30f;
        if (j < end) { sj = ssrc[j]; sc = lrelu(as_[sj] + add); }
        float cm = sc;
        #pragma unroll
        for (int off = 32; off > 0; off >>= 1) cm = fmaxf(cm, __shfl_xor(cm, off));
        float nm = fmaxf(m, cm);
        float scale = __expf(m - nm);
        float ex = (j < end) ? __expf(sc - nm) : 0.f;
        float cs = ex;
        #pragma unroll
        for (int off = 32; off > 0; off >>= 1) cs += __shfl_xor(cs, off);
        l = l * scale + cs;
        #pragma unroll
        for (int c = 0; c < 4; ++c) acc[c] *= scale;
        m = nm;

        pairs[lane] = make_uint2(__float_as_uint(ex), ((u32)sj) << 6);
        __builtin_amdgcn_wave_barrier();
        asm volatile("s_waitcnt lgkmcnt(0)" ::: "memory");

        const int cnt = min(64, end - base);
        const int ngrp = (cnt + 7) >> 3;          // 8-edge groups, <= 8

        {   // single batch: all groups issued before any FMA
            const int nb = ngrp;
            uint2 pv[8], qv[8];
            #pragma unroll
            for (int k = 0; k < 8; ++k) if (k < nb) pv[k] = pairs[(k << 3) + e8];
            #pragma unroll
            for (int k = 0; k < 8; ++k) if (k < nb)
                qv[k] = *(const uint2*)(hb + (size_t)(pv[k].y + boff));
            #pragma unroll
            for (int k = 0; k < 8; ++k) if (k < nb) {
                float w = __uint_as_float(pv[k].x);
                acc[0] = fmaf(w, __uint_as_float(qv[k].x << 16), acc[0]);
                acc[1] = fmaf(w, __uint_as_float(qv[k].x & 0xFFFF0000u), acc[1]);
                acc[2] = fmaf(w, __uint_as_float(qv[k].y << 16), acc[2]);
                acc[3] = fmaf(w, __uint_as_float(qv[k].y & 0xFFFF0000u), acc[3]);
            }
        }
        __builtin_amdgcn_wave_barrier();   // keep reads before next block's write
    }
    #pragma unroll
    for (int c = 0; c < 4; ++c) {
        acc[c] += __shfl_xor(acc[c], 8);
        acc[c] += __shfl_xor(acc[c], 16);
        acc[c] += __shfl_xor(acc[c], 32);
    }

    // fused bias + log_softmax: 8 lanes x 4 channels (replicated across groups)
    float inv = 1.f / l;
    float v[4];
    #pragma unroll
    for (int c = 0; c < 4; ++c) v[c] = acc[c] * inv + ldf(b2, 4 * i8 + c, bf);
    float mx = fmaxf(fmaxf(v[0], v[1]), fmaxf(v[2], v[3]));
    #pragma unroll
    for (int off = 1; off < 8; off <<= 1) mx = fmaxf(mx, __shfl_xor(mx, off));
    float ss = __expf(v[0] - mx) + __expf(v[1] - mx) + __expf(v[2] - mx) + __expf(v[3] - mx);
    #pragma unroll
    for (int off = 1; off < 8; off <<= 1) ss += __shfl_xor(ss, off);
    float lg = mx + __logf(ss);
    if (lane < 8)
        *(float4*)&out[(size_t)dst * 32 + 4 * i8] =
            make_float4(v[0] - lg, v[1] - lg, v[2] - lg, v[3] - lg);
}

// ---------------------------------------------------------------------------
// GEMM2: hin = relu(agg1 + b1); h2[N,32](bf16) = hin @ W[64,32].
// 128-node tile, 256 threads, 4 nodes x 4 channels per thread.
// ---------------------------------------------------------------------------
#define G2_TILE 128

__global__ __launch_bounds__(256, 3) void gemm2_kernel(
    const float* __restrict__ agg1, const void* __restrict__ b1,
    const u32* __restrict__ W32, const void* __restrict__ a_src,
    const void* __restrict__ a_dst, const int* __restrict__ flags,
    u16* __restrict__ h, float* __restrict__ as_, float* __restrict__ ad_)
{
    __shared__ __align__(16) float Wl[64 * 32];        // 8 KB
    __shared__ __align__(16) float xs[G2_TILE * 68];   // 34.8 KB
    const int tid = threadIdx.x;
    const int node0 = blockIdx.x * G2_TILE;
    const int bf = flags[0];

    // stage W2 as f32
    if (bf) {
        for (int i = tid; i < 1024; i += 256) {
            u32 u = W32[i];
            *(float2*)&Wl[2 * i] = make_float2(__uint_as_float(u << 16),
                                               __uint_as_float(u & 0xFFFF0000u));
        }
    } else {
        for (int i = tid; i < 2048; i += 256) Wl[i] = __uint_as_float(W32[i]);
    }
    // stage hin = relu(agg1 + b1), float4-coalesced
    #pragma unroll
    for (int it = 0; it < 8; ++it) {
        int i = tid + it * 256;           // [0, 2048)
        int nl = i >> 4;                  // local node 0..127
        int k  = (i & 15) * 4;
        int n = node0 + nl;
        float4 v = make_float4(0.f, 0.f, 0.f, 0.f);
        if (n < N_NODES) v = *(const float4*)(agg1 + (size_t)n * 64 + k);
        v.x = fmaxf(v.x + ldf(b1, k + 0, bf), 0.f);
        v.y = fmaxf(v.y + ldf(b1, k + 1, bf), 0.f);
        v.z = fmaxf(v.z + ldf(b1, k + 2, bf), 0.f);
        v.w = fmaxf(v.w + ldf(b1, k + 3, bf), 0.f);
        *(float4*)&xs[nl * 68 + k] = v;
    }
    __syncthreads();

    const int ch0 = (tid & 7) * 4;        // 4 output channels
    const int nb0 = (tid >> 3) * 4;       // 4 local nodes
    float acc[4][4];
    #pragma unroll
    for (int j = 0; j < 4; ++j)
        #pragma unroll
        for (int c = 0; c < 4; ++c) acc[j][c] = 0.f;

    #pragma unroll 4
    for (int k0 = 0; k0 < 64; k0 += 4) {
        float4 xv0 = *(const float4*)&xs[(nb0 + 0) * 68 + k0];
        float4 xv1 = *(const float4*)&xs[(nb0 + 1) * 68 + k0];
        float4 xv2 = *(const float4*)&xs[(nb0 + 2) * 68 + k0];
        float4 xv3 = *(const float4*)&xs[(nb0 + 3) * 68 + k0];
        const float* xp[4] = { (const float*)&xv0, (const float*)&xv1,
                               (const float*)&xv2, (const float*)&xv3 };
        #pragma unroll
        for (int kk = 0; kk < 4; ++kk) {
            float4 w = *(const float4*)&Wl[(k0 + kk) * 32 + ch0];
            #pragma unroll
            for (int j = 0; j < 4; ++j) {
                float xvv = xp[j][kk];
                acc[j][0] = fmaf(xvv, w.x, acc[j][0]);
                acc[j][1] = fmaf(xvv, w.y, acc[j][1]);
                acc[j][2] = fmaf(xvv, w.z, acc[j][2]);
                acc[j][3] = fmaf(xvv, w.w, acc[j][3]);
            }
        }
    }

    float av[4], dv[4];
    #pragma unroll
    for (int c = 0; c < 4; ++c) {
        av[c] = ldf(a_src, ch0 + c, bf);
        dv[c] = ldf(a_dst, ch0 + c, bf);
    }
    #pragma unroll
    for (int j = 0; j < 4; ++j) {
        float ps = acc[j][0] * av[0] + acc[j][1] * av[1]
                 + acc[j][2] * av[2] + acc[j][3] * av[3];
        float pd = acc[j][0] * dv[0] + acc[j][1] * dv[1]
                 + acc[j][2] * dv[2] + acc[j][3] * dv[3];
        #pragma unroll
        for (int off = 1; off < 8; off <<= 1) {
            ps += __shfl_xor(ps, off);
            pd += __shfl_xor(pd, off);
        }
        int n = node0 + nb0 + j;
        if (n < N_NODES) {
            u32 p0 = (u32)f2bf(acc[j][0]) | ((u32)f2bf(acc[j][1]) << 16);
            u32 p1 = (u32)f2bf(acc[j][2]) | ((u32)f2bf(acc[j][3]) << 16);
            *(uint2*)&h[(size_t)n * 32 + ch0] = make_uint2(p0, p1);
            if ((tid & 7) == 0) { as_[n] = ps; ad_[n] = pd; }
        }
    }
}

// ---------------------------------------------------------------------------
extern "C" void kernel_launch(void* const* d_in, const int* in_sizes, int n_in,
                              void* d_out, int out_size, void* d_ws, size_t ws_size,
                              hipStream_t stream) {
    const float* x   = (const float*)d_in[0];
    const int* ei    = (const int*)d_in[1];
    const float* W1  = (const float*)d_in[2];
    const void* a_s1 = d_in[3];
    const void* a_d1 = d_in[4];
    const void* b1   = d_in[5];
    const u32* W2    = (const u32*)d_in[6];
    const void* a_s2 = d_in[7];
    const void* a_d2 = d_in[8];
    const void* b2   = d_in[9];
    float* out = (float*)d_out;

    // workspace carve-up (~55 MB)
    char* base = (char*)d_ws;
    int* flags = (int*)base;
    u16* h     = (u16*)(base + 64);                           // N*64 bf16 (reused N*32)
    char* q = base + 64 + (size_t)N_NODES * 64 * 2;
    float* as1 = (float*)q; q += (size_t)N_NODES * 4;
    float* ad1 = (float*)q; q += (size_t)N_NODES * 4;
    float* as2 = (float*)q; q += (size_t)N_NODES * 4;
    float* ad2 = (float*)q; q += (size_t)N_NODES * 4;
    float* agg1 = (float*)q; q += (size_t)N_NODES * 64 * 4;
    u32*  bbuf  = (u32*)q;  q += (size_t)NBUCK * BCAP * 4;    // 8.03 MB
    int* rowptr = (int*)q;  q += (size_t)(N_NODES + 16) * 4;
    int* ssrc   = (int*)q;  q += (size_t)ET * 4;
    int* bcnt   = (int*)q;  q += 256 * 4;
    int* bbase  = (int*)q;  q += 256 * 4;

    detect_kernel<<<1, 64, 0, stream>>>((const u32*)x, ei, flags, bcnt);

    // CSR by dst via 2-pass bucket sort (rowptr built in scatter)
    bin_kernel<<<(ET + BINCH - 1) / BINCH, 256, 0, stream>>>(ei, flags, bcnt, bbuf);
    bscan_kernel<<<1, 256, 0, stream>>>(bcnt, bbase);
    scatter_kernel<<<NBUCK, 1024, 0, stream>>>(bcnt, bbase, bbuf, rowptr, ssrc);

    // layer 1
    gemm1_kernel<<<(N_NODES + 255) / 256, 256, 0, stream>>>(x, W1, a_s1, a_d1, flags, h, as1, ad1);
    gat_agg64_kernel<<<(N_NODES + 3) / 4, 256, 0, stream>>>(rowptr, ssrc, as1, ad1, h, agg1);

    // layer 2 (lsm fused; writes d_out directly)
    gemm2_kernel<<<(N_NODES + G2_TILE - 1) / G2_TILE, 256, 0, stream>>>(agg1, b1, W2, a_s2, a_d2, flags, h, as2, ad2);
    gat_agg32_lsm_kernel<<<(N_NODES + 3) / 4, 256, 0, stream>>>(rowptr, ssrc, as2, ad2, h, b2, flags, out);
}

// Round 5
// 317.305 us; speedup vs baseline: 1.1025x; 1.1025x over previous
//
#include <hip/hip_runtime.h>

#define N_NODES 100000
#define N_EDGES 1600000
#define ET (N_EDGES + N_NODES)
#define NEG_SLOPE 0.2f

// bucket sort params
#define BSHIFT 9
#define BW 512                                  // nodes per bucket
#define NBUCK ((N_NODES + BW - 1) / BW)         // 196
#define BCAP 10240
#define BINCH 2048                              // edges per bin block

typedef unsigned short u16;
typedef unsigned int u32;

__device__ __forceinline__ float bf2f(u16 v) {
    return __uint_as_float(((u32)v) << 16);
}
__device__ __forceinline__ u16 f2bf(float f) {
    u32 u = __float_as_uint(f);
    u32 r = (u + 0x7FFFu + ((u >> 16) & 1u)) >> 16;  // RNE
    return (u16)r;
}
__device__ __forceinline__ float lrelu(float x) { return x > 0.f ? x : NEG_SLOPE * x; }
__device__ __forceinline__ float ldf(const void* p, int i, int bf) {
    return bf ? bf2f(((const u16*)p)[i]) : ((const float*)p)[i];
}
__device__ __forceinline__ int get_dst(const int* __restrict__ ei, int e, int ei64) {
    if (e < N_EDGES) return ei64 ? ei[2 * (N_EDGES + e)] : ei[N_EDGES + e];
    return e - N_EDGES;
}
__device__ __forceinline__ int get_src(const int* __restrict__ ei, int e, int ei64) {
    if (e < N_EDGES) return ei64 ? ei[2 * e] : ei[e];
    return e - N_EDGES;
}

// 8 bf16-channel FMA from one uint4 (16 B of an h row)
__device__ __forceinline__ void fma8(float wt, uint4 qv, float (&acc)[8]) {
    acc[0] = fmaf(wt, __uint_as_float(qv.x << 16), acc[0]);
    acc[1] = fmaf(wt, __uint_as_float(qv.x & 0xFFFF0000u), acc[1]);
    acc[2] = fmaf(wt, __uint_as_float(qv.y << 16), acc[2]);
    acc[3] = fmaf(wt, __uint_as_float(qv.y & 0xFFFF0000u), acc[3]);
    acc[4] = fmaf(wt, __uint_as_float(qv.z << 16), acc[4]);
    acc[5] = fmaf(wt, __uint_as_float(qv.z & 0xFFFF0000u), acc[5]);
    acc[6] = fmaf(wt, __uint_as_float(qv.w << 16), acc[6]);
    acc[7] = fmaf(wt, __uint_as_float(qv.w & 0xFFFF0000u), acc[7]);
}

// ---------------------------------------------------------------------------
// Detect input storage + zero bcnt (memset dispatch folded in).
// ---------------------------------------------------------------------------
__global__ void detect_kernel(const u32* __restrict__ x32, const int* __restrict__ ei,
                              int* __restrict__ flags, int* __restrict__ bcnt) {
    int lane = threadIdx.x;  // 64
    for (int i = lane; i < 256; i += 64) bcnt[i] = 0;
    u32 e = (x32[lane] >> 7) & 0xFFu;
    int ok = (e >= 96u && e <= 143u) ? 1 : 0;
    int cnt = (int)__popcll(__ballot(ok));
    int nz = (ei[2 * lane + 1] != 0) + (ei[2 * (lane + 64) + 1] != 0);
    #pragma unroll
    for (int off = 32; off > 0; off >>= 1) nz += __shfl_xor(nz, off);
    if (lane == 0) { flags[0] = (cnt >= 48) ? 1 : 0; flags[1] = (nz == 0) ? 1 : 0; }
}

// ---------------------------------------------------------------------------
// Pass 1: bin edges by dst>>9 into 196 buckets; code = (dst&511)<<17 | src.
// ---------------------------------------------------------------------------
__global__ __launch_bounds__(256) void bin_kernel(
    const int* __restrict__ ei, const int* __restrict__ flags,
    int* __restrict__ bcnt, u32* __restrict__ bbuf)
{
    __shared__ int hist[NBUCK];
    const int t = threadIdx.x;
    const int base = blockIdx.x * BINCH;
    const int ei64 = flags[1];
    for (int i = t; i < NBUCK; i += 256) hist[i] = 0;
    __syncthreads();
    for (int i = t; i < BINCH; i += 256) {
        int e = base + i;
        if (e >= ET) break;
        int d = get_dst(ei, e, ei64);
        atomicAdd(&hist[d >> BSHIFT], 1);
    }
    __syncthreads();
    for (int i = t; i < NBUCK; i += 256) {
        int c = hist[i];
        hist[i] = (c > 0) ? atomicAdd(&bcnt[i], c) : 0;
    }
    __syncthreads();
    for (int i = t; i < BINCH; i += 256) {
        int e = base + i;
        if (e >= ET) break;
        int d = get_dst(ei, e, ei64);
        int s = get_src(ei, e, ei64);
        int b = d >> BSHIFT;
        int pos = atomicAdd(&hist[b], 1);
        if (pos < BCAP)
            bbuf[(size_t)b * BCAP + pos] = ((u32)(d & (BW - 1)) << 17) | (u32)s;
    }
}

// exclusive scan of clamped bucket counts -> bbase[NBUCK+1]
__global__ __launch_bounds__(256) void bscan_kernel(
    const int* __restrict__ bcnt, int* __restrict__ bbase)
{
    __shared__ int sd[256];
    int t = threadIdx.x;
    int v = (t < NBUCK) ? min(bcnt[t], BCAP) : 0;
    sd[t] = v;
    __syncthreads();
    for (int off = 1; off < 256; off <<= 1) {
        int x = (t >= off) ? sd[t - off] : 0;
        __syncthreads();
        sd[t] += x;
        __syncthreads();
    }
    if (t < NBUCK) bbase[t] = sd[t] - v;
    if (t == NBUCK - 1) bbase[NBUCK] = sd[t];
}

// ---------------------------------------------------------------------------
// Pass 2: one block (1024 threads) per bucket -> rowptr + dst-sorted ssrc.
// ---------------------------------------------------------------------------
__global__ __launch_bounds__(1024) void scatter_kernel(
    const int* __restrict__ bcnt, const int* __restrict__ bbase,
    const u32* __restrict__ bbuf, int* __restrict__ rowptr, int* __restrict__ ssrc)
{
    __shared__ int hist[BW];
    __shared__ int cur[BW];
    __shared__ int wtot[4];
    __shared__ int lds_s[BCAP];
    const int t = threadIdx.x;
    const int b = blockIdx.x;
    const int cnt = min(bcnt[b], BCAP);
    const int base = bbase[b];
    const u32* mybuf = bbuf + (size_t)b * BCAP;

    if (t < BW) hist[t] = 0;
    __syncthreads();
    for (int i = t; i < cnt; i += 1024) atomicAdd(&hist[(int)(mybuf[i] >> 17)], 1);
    __syncthreads();
    int a0 = 0, a1 = 0, s = 0, v = 0;
    const int lane = t & 63, wid = t >> 6;
    if (t < 256) {
        a0 = hist[2 * t]; a1 = hist[2 * t + 1];
        s = a0 + a1;
        v = s;
        #pragma unroll
        for (int off = 1; off < 64; off <<= 1) {
            int n = __shfl_up(v, off);
            if (lane >= off) v += n;
        }
        if (lane == 63) wtot[wid] = v;
    }
    __syncthreads();
    if (t == 0) {
        int acc = 0;
        #pragma unroll
        for (int w = 0; w < 4; ++w) { int tmp = wtot[w]; wtot[w] = acc; acc += tmp; }
    }
    __syncthreads();
    if (t < 256) {
        int excl = v + wtot[wid] - s;
        cur[2 * t] = excl;
        cur[2 * t + 1] = excl + a0;
    }
    __syncthreads();
    if (t < BW) {
        int g = b * BW + t;
        if (g < N_NODES) rowptr[g] = base + cur[t];
    }
    if (b == NBUCK - 1 && t == 0) rowptr[N_NODES] = bbase[NBUCK];
    __syncthreads();
    for (int i = t; i < cnt; i += 1024) {
        u32 code = mybuf[i];
        int pos = atomicAdd(&cur[(int)(code >> 17)], 1);
        lds_s[pos] = (int)(code & 0x1FFFFu);
    }
    __syncthreads();
    for (int i = t; i < cnt; i += 1024) ssrc[base + i] = lds_s[i];
}

// ---------------------------------------------------------------------------
// GEMM1: h[N,64](bf16) = x[N,128] @ W[128,64]; as_/ad_ score dots.
// ---------------------------------------------------------------------------
__global__ __launch_bounds__(256) void gemm1_kernel(
    const float* __restrict__ x, const float* __restrict__ W,
    const void* __restrict__ a_src, const void* __restrict__ a_dst,
    const int* __restrict__ flags,
    u16* __restrict__ h, float* __restrict__ as_, float* __restrict__ ad_)
{
    __shared__ float xs[256 * 33];   // 33.8 KB
    __shared__ float Wl[32 * 64];    // 8 KB
    const int t = threadIdx.x;
    const int node0 = blockIdx.x * 256;
    const int bf = flags[0];
    const int ng = t >> 3;
    const int cg = t & 7;

    float acc[8][8];
    #pragma unroll
    for (int i = 0; i < 8; ++i)
        #pragma unroll
        for (int j = 0; j < 8; ++j) acc[i][j] = 0.f;

    for (int kc = 0; kc < 4; ++kc) {
        const int kb = kc * 32;
        const int c4 = t & 7;
        #pragma unroll
        for (int p = 0; p < 8; ++p) {
            int row = (t >> 3) + p * 32;
            int n = node0 + row;
            float4 vv = make_float4(0.f, 0.f, 0.f, 0.f);
            if (n < N_NODES) {
                if (!bf) {
                    vv = *(const float4*)(x + (size_t)n * 128 + kb + c4 * 4);
                } else {
                    const u16* xh = (const u16*)x;
                    vv.x = bf2f(xh[(size_t)n * 128 + kb + c4 * 4 + 0]);
                    vv.y = bf2f(xh[(size_t)n * 128 + kb + c4 * 4 + 1]);
                    vv.z = bf2f(xh[(size_t)n * 128 + kb + c4 * 4 + 2]);
                    vv.w = bf2f(xh[(size_t)n * 128 + kb + c4 * 4 + 3]);
                }
            }
            float* dstp = &xs[row * 33 + c4 * 4];
            dstp[0] = vv.x; dstp[1] = vv.y; dstp[2] = vv.z; dstp[3] = vv.w;
        }
        if (!bf) {
            #pragma unroll
            for (int qq = 0; qq < 2; ++qq) {
                int f4 = t * 2 + qq;
                ((float4*)Wl)[f4] = ((const float4*)(W + (size_t)kb * 64))[f4];
            }
        } else {
            const u16* Wh = (const u16*)W;
            for (int i = t; i < 2048; i += 256) Wl[i] = bf2f(Wh[(size_t)kb * 64 + i]);
        }
        __syncthreads();

        for (int kk = 0; kk < 32; ++kk) {
            float xr[8];
            #pragma unroll
            for (int i = 0; i < 8; ++i) xr[i] = xs[(ng * 8 + i) * 33 + kk];
            float4 w0 = *(const float4*)&Wl[kk * 64 + cg * 8];
            float4 w1 = *(const float4*)&Wl[kk * 64 + cg * 8 + 4];
            const float wr[8] = {w0.x, w0.y, w0.z, w0.w, w1.x, w1.y, w1.z, w1.w};
            #pragma unroll
            for (int i = 0; i < 8; ++i)
                #pragma unroll
                for (int j = 0; j < 8; ++j)
                    acc[i][j] = fmaf(xr[i], wr[j], acc[i][j]);
        }
        __syncthreads();
    }

    float av[8], dv[8];
    #pragma unroll
    for (int j = 0; j < 8; ++j) {
        av[j] = ldf(a_src, cg * 8 + j, bf);
        dv[j] = ldf(a_dst, cg * 8 + j, bf);
    }
    #pragma unroll
    for (int i = 0; i < 8; ++i) {
        int n = node0 + ng * 8 + i;
        float ps = 0.f, pd = 0.f;
        #pragma unroll
        for (int j = 0; j < 8; ++j) { ps += acc[i][j] * av[j]; pd += acc[i][j] * dv[j]; }
        #pragma unroll
        for (int off = 1; off < 8; off <<= 1) {
            ps += __shfl_xor(ps, off);
            pd += __shfl_xor(pd, off);
        }
        if (n < N_NODES) {
            uint4 hv;
            hv.x = (u32)f2bf(acc[i][0]) | ((u32)f2bf(acc[i][1]) << 16);
            hv.y = (u32)f2bf(acc[i][2]) | ((u32)f2bf(acc[i][3]) << 16);
            hv.z = (u32)f2bf(acc[i][4]) | ((u32)f2bf(acc[i][5]) << 16);
            hv.w = (u32)f2bf(acc[i][6]) | ((u32)f2bf(acc[i][7]) << 16);
            *(uint4*)&h[(size_t)n * 64 + cg * 8] = hv;
            if (cg == 0) { as_[n] = ps; ad_[n] = pd; }
        }
    }
}

// ---------------------------------------------------------------------------
// Layer-1 aggregation, C=64. One wave per dst. r4: branch-free uint4 gather,
// 8 lanes/edge, 8-edge groups. Degree is Poisson(17): deg<=64 for ~all dsts
// -> single-block fast path (no running softmax). Loads for edges 0..31 are
// issued BEFORE the softmax shfl chain (addresses depend only on sj), hiding
// gather latency under compute. Invalid edges carry sj=0/ex=0: they read
// h[0] (L1-hot broadcast) with weight 0. bpermute (__shfl) replaces the LDS
// pair table -> no LDS, no barriers. r3's lesson: per-element conditionals
// serialized the loads (each in own basic block); keep hot path straight-line.
// ---------------------------------------------------------------------------
__global__ __launch_bounds__(256) void gat_agg64_kernel(
    const int* __restrict__ rowptr, const int* __restrict__ ssrc,
    const float* __restrict__ as_, const float* __restrict__ ad_,
    const u16* __restrict__ h, float* __restrict__ agg)
{
    const int lane = threadIdx.x & 63;
    const int dst = blockIdx.x * 4 + (threadIdx.x >> 6);
    if (dst >= N_NODES) return;
    const int beg = rowptr[dst], end = rowptr[dst + 1];
    const int deg = end - beg;
    const float add = ad_[dst];
    const int e8 = lane >> 3;                      // edge within group of 8
    const int i8 = lane & 7;                       // uint4 index within 128-B row
    const char* __restrict__ hb = (const char*)h;
    const u32 boff = (u32)(i8 * 16);

    float acc[8] = {0.f, 0.f, 0.f, 0.f, 0.f, 0.f, 0.f, 0.f};
    float l;

    if (deg <= 64) {
        int j = beg + lane;
        bool valid = j < end;
        int sj = valid ? ssrc[j] : 0;
        float asv = as_[sj];                       // score gather, issued early
        int row = sj << 7;                         // h row byte offset
        // group addresses via bpermute; issue h loads before softmax
        int a0 = __shfl(row, e8);
        int a1 = __shfl(row, 8 + e8);
        int a2 = __shfl(row, 16 + e8);
        int a3 = __shfl(row, 24 + e8);
        uint4 q0 = *(const uint4*)(hb + (size_t)((u32)a0 + boff));
        uint4 q1 = *(const uint4*)(hb + (size_t)((u32)a1 + boff));
        uint4 q2 = *(const uint4*)(hb + (size_t)((u32)a2 + boff));
        uint4 q3 = *(const uint4*)(hb + (size_t)((u32)a3 + boff));

        float sc = valid ? lrelu(asv + add) : -1e30f;
        float m = sc;
        #pragma unroll
        for (int off = 32; off > 0; off >>= 1) m = fmaxf(m, __shfl_xor(m, off));
        float ex = __expf(sc - m);                 // invalid lanes underflow to 0
        l = ex;
        #pragma unroll
        for (int off = 32; off > 0; off >>= 1) l += __shfl_xor(l, off);

        float w0 = __shfl(ex, e8);
        float w1 = __shfl(ex, 8 + e8);
        float w2 = __shfl(ex, 16 + e8);
        float w3 = __shfl(ex, 24 + e8);
        fma8(w0, q0, acc); fma8(w1, q1, acc); fma8(w2, q2, acc); fma8(w3, q3, acc);

        if (deg > 32) {                            // rare (P ~ 5e-5)
            int b0 = __shfl(row, 32 + e8);
            int b1 = __shfl(row, 40 + e8);
            int b2_ = __shfl(row, 48 + e8);
            int b3 = __shfl(row, 56 + e8);
            uint4 r0 = *(const uint4*)(hb + (size_t)((u32)b0 + boff));
            uint4 r1 = *(const uint4*)(hb + (size_t)((u32)b1 + boff));
            uint4 r2 = *(const uint4*)(hb + (size_t)((u32)b2_ + boff));
            uint4 r3 = *(const uint4*)(hb + (size_t)((u32)b3 + boff));
            float u0 = __shfl(ex, 32 + e8);
            float u1 = __shfl(ex, 40 + e8);
            float u2 = __shfl(ex, 48 + e8);
            float u3 = __shfl(ex, 56 + e8);
            fma8(u0, r0, acc); fma8(u1, r1, acc); fma8(u2, r2, acc); fma8(u3, r3, acc);
        }
    } else {
        // slow path (deg > 64, ~never for this graph): running softmax
        float m = -1e30f;
        l = 0.f;
        for (int base = beg; base < end; base += 64) {
            int j = base + lane;
            bool valid = j < end;
            int sj = valid ? ssrc[j] : 0;
            float asv = as_[sj];
            int row = sj << 7;
            int a0 = __shfl(row, e8);
            int a1 = __shfl(row, 8 + e8);
            int a2 = __shfl(row, 16 + e8);
            int a3 = __shfl(row, 24 + e8);
            uint4 q0 = *(const uint4*)(hb + (size_t)((u32)a0 + boff));
            uint4 q1 = *(const uint4*)(hb + (size_t)((u32)a1 + boff));
            uint4 q2 = *(const uint4*)(hb + (size_t)((u32)a2 + boff));
            uint4 q3 = *(const uint4*)(hb + (size_t)((u32)a3 + boff));

            float sc = valid ? lrelu(asv + add) : -1e30f;
            float cm = sc;
            #pragma unroll
            for (int off = 32; off > 0; off >>= 1) cm = fmaxf(cm, __shfl_xor(cm, off));
            float nm = fmaxf(m, cm);
            float scale = __expf(m - nm);
            float ex = __expf(sc - nm);
            float cs = ex;
            #pragma unroll
            for (int off = 32; off > 0; off >>= 1) cs += __shfl_xor(cs, off);
            l = l * scale + cs;
            #pragma unroll
            for (int c = 0; c < 8; ++c) acc[c] *= scale;
            m = nm;

            float w0 = __shfl(ex, e8);
            float w1 = __shfl(ex, 8 + e8);
            float w2 = __shfl(ex, 16 + e8);
            float w3 = __shfl(ex, 24 + e8);
            fma8(w0, q0, acc); fma8(w1, q1, acc); fma8(w2, q2, acc); fma8(w3, q3, acc);

            int cnt = min(64, end - base);
            if (cnt > 32) {
                int b0 = __shfl(row, 32 + e8);
                int b1 = __shfl(row, 40 + e8);
                int b2_ = __shfl(row, 48 + e8);
                int b3 = __shfl(row, 56 + e8);
                uint4 r0 = *(const uint4*)(hb + (size_t)((u32)b0 + boff));
                uint4 r1 = *(const uint4*)(hb + (size_t)((u32)b1 + boff));
                uint4 r2 = *(const uint4*)(hb + (size_t)((u32)b2_ + boff));
                uint4 r3 = *(const uint4*)(hb + (size_t)((u32)b3 + boff));
                float u0 = __shfl(ex, 32 + e8);
                float u1 = __shfl(ex, 40 + e8);
                float u2 = __shfl(ex, 48 + e8);
                float u3 = __shfl(ex, 56 + e8);
                fma8(u0, r0, acc); fma8(u1, r1, acc); fma8(u2, r2, acc); fma8(u3, r3, acc);
            }
        }
    }

    // reduce over e8 (8 edge-slots), lanes with e8==0 hold channels i8*8..+7
    #pragma unroll
    for (int c = 0; c < 8; ++c) {
        acc[c] += __shfl_xor(acc[c], 8);
        acc[c] += __shfl_xor(acc[c], 16);
        acc[c] += __shfl_xor(acc[c], 32);
    }
    if (e8 == 0) {
        float inv = 1.f / l;
        *(float4*)&agg[(size_t)dst * 64 + i8 * 8] =
            make_float4(acc[0] * inv, acc[1] * inv, acc[2] * inv, acc[3] * inv);
        *(float4*)&agg[(size_t)dst * 64 + i8 * 8 + 4] =
            make_float4(acc[4] * inv, acc[5] * inv, acc[6] * inv, acc[7] * inv);
    }
}

// ---------------------------------------------------------------------------
// Layer-2 aggregation, C=32. r4: same branch-free uint4 scheme (4 lanes/edge,
// 16-edge groups; 2 unconditional groups cover deg<=32). Fused bias +
// log_softmax over 4 lanes x 8 channels.
// ---------------------------------------------------------------------------
__global__ __launch_bounds__(256) void gat_agg32_lsm_kernel(
    const int* __restrict__ rowptr, const int* __restrict__ ssrc,
    const float* __restrict__ as_, const float* __restrict__ ad_,
    const u16* __restrict__ h, const void* __restrict__ b2,
    const int* __restrict__ flags, float* __restrict__ out)
{
    const int lane = threadIdx.x & 63;
    const int dst = blockIdx.x * 4 + (threadIdx.x >> 6);
    if (dst >= N_NODES) return;
    const int beg = rowptr[dst], end = rowptr[dst + 1];
    const int deg = end - beg;
    const float add = ad_[dst];
    const int e16 = lane >> 2;                    // edge within group of 16
    const int i4 = lane & 3;                      // uint4 index within 64-B row
    const int bf = flags[0];
    const char* __restrict__ hb = (const char*)h;
    const u32 boff = (u32)(i4 * 16);

    float acc[8] = {0.f, 0.f, 0.f, 0.f, 0.f, 0.f, 0.f, 0.f};
    float l;

    if (deg <= 64) {
        int j = beg + lane;
        bool valid = j < end;
        int sj = valid ? ssrc[j] : 0;
        float asv = as_[sj];
        int row = sj << 6;
        int a0 = __shfl(row, e16);
        int a1 = __shfl(row, 16 + e16);
        uint4 q0 = *(const uint4*)(hb + (size_t)((u32)a0 + boff));
        uint4 q1 = *(const uint4*)(hb + (size_t)((u32)a1 + boff));

        float sc = valid ? lrelu(asv + add) : -1e30f;
        float m = sc;
        #pragma unroll
        for (int off = 32; off > 0; off >>= 1) m = fmaxf(m, __shfl_xor(m, off));
        float ex = __expf(sc - m);
        l = ex;
        #pragma unroll
        for (int off = 32; off > 0; off >>= 1) l += __shfl_xor(l, off);

        float w0 = __shfl(ex, e16);
        float w1 = __shfl(ex, 16 + e16);
        fma8(w0, q0, acc); fma8(w1, q1, acc);

        if (deg > 32) {                            // rare
            int a2 = __shfl(row, 32 + e16);
            int a3 = __shfl(row, 48 + e16);
            uint4 q2 = *(const uint4*)(hb + (size_t)((u32)a2 + boff));
            uint4 q3 = *(const uint4*)(hb + (size_t)((u32)a3 + boff));
            float w2 = __shfl(ex, 32 + e16);
            float w3 = __shfl(ex, 48 + e16);
            fma8(w2, q2, acc); fma8(w3, q3, acc);
        }
    } else {
        float m = -1e30f;
        l = 0.f;
        for (int base = beg; base < end; base += 64) {
            int j = base + lane;
            bool valid = j < end;
            int sj = valid ? ssrc[j] : 0;
            float asv = as_[sj];
            int row = sj << 6;
            int a0 = __shfl(row, e16);
            int a1 = __shfl(row, 16 + e16);
            uint4 q0 = *(const uint4*)(hb + (size_t)((u32)a0 + boff));
            uint4 q1 = *(const uint4*)(hb + (size_t)((u32)a1 + boff));

            float sc = valid ? lrelu(asv + add) : -1e30f;
            float cm = sc;
            #pragma unroll
            for (int off = 32; off > 0; off >>= 1) cm = fmaxf(cm, __shfl_xor(cm, off));
            float nm = fmaxf(m, cm);
            float scale = __expf(m - nm);
            float ex = __expf(sc - nm);
            float cs = ex;
            #pragma unroll
            for (int off = 32; off > 0; off >>= 1) cs += __shfl_xor(cs, off);
            l = l * scale + cs;
            #pragma unroll
            for (int c = 0; c < 8; ++c) acc[c] *= scale;
            m = nm;

            float w0 = __shfl(ex, e16);
            float w1 = __shfl(ex, 16 + e16);
            fma8(w0, q0, acc); fma8(w1, q1, acc);

            int cnt = min(64, end - base);
            if (cnt > 32) {
                int a2 = __shfl(row, 32 + e16);
                int a3 = __shfl(row, 48 + e16);
                uint4 q2 = *(const uint4*)(hb + (size_t)((u32)a2 + boff));
                uint4 q3 = *(const uint4*)(hb + (size_t)((u32)a3 + boff));
                float w2 = __shfl(ex, 32 + e16);
                float w3 = __shfl(ex, 48 + e16);
                fma8(w2, q2, acc); fma8(w3, q3, acc);
            }
        }
    }

    // reduce over e16 (16 edge-slots); lanes 0..3 hold channels i4*8..+7
    #pragma unroll
    for (int c = 0; c < 8; ++c) {
        acc[c] += __shfl_xor(acc[c], 4);
        acc[c] += __shfl_xor(acc[c], 8);
        acc[c] += __shfl_xor(acc[c], 16);
        acc[c] += __shfl_xor(acc[c], 32);
    }

    // fused bias + log_softmax: 4 lanes x 8 channels (replicated across e16)
    float inv = 1.f / l;
    float v[8];
    #pragma unroll
    for (int c = 0; c < 8; ++c) v[c] = acc[c] * inv + ldf(b2, i4 * 8 + c, bf);
    float mx = v[0];
    #pragma unroll
    for (int c = 1; c < 8; ++c) mx = fmaxf(mx, v[c]);
    #pragma unroll
    for (int off = 1; off < 4; off <<= 1) mx = fmaxf(mx, __shfl_xor(mx, off));
    float ss = 0.f;
    #pragma unroll
    for (int c = 0; c < 8; ++c) ss += __expf(v[c] - mx);
    #pragma unroll
    for (int off = 1; off < 4; off <<= 1) ss += __shfl_xor(ss, off);
    float lg = mx + __logf(ss);
    if (lane < 4) {
        *(float4*)&out[(size_t)dst * 32 + i4 * 8] =
            make_float4(v[0] - lg, v[1] - lg, v[2] - lg, v[3] - lg);
        *(float4*)&out[(size_t)dst * 32 + i4 * 8 + 4] =
            make_float4(v[4] - lg, v[5] - lg, v[6] - lg, v[7] - lg);
    }
}

// ---------------------------------------------------------------------------
// GEMM2: hin = relu(agg1 + b1); h2[N,32](bf16) = hin @ W[64,32].
// 128-node tile, 256 threads, 4 nodes x 4 channels per thread.
// ---------------------------------------------------------------------------
#define G2_TILE 128

__global__ __launch_bounds__(256, 3) void gemm2_kernel(
    const float* __restrict__ agg1, const void* __restrict__ b1,
    const u32* __restrict__ W32, const void* __restrict__ a_src,
    const void* __restrict__ a_dst, const int* __restrict__ flags,
    u16* __restrict__ h, float* __restrict__ as_, float* __restrict__ ad_)
{
    __shared__ __align__(16) float Wl[64 * 32];        // 8 KB
    __shared__ __align__(16) float xs[G2_TILE * 68];   // 34.8 KB
    const int tid = threadIdx.x;
    const int node0 = blockIdx.x * G2_TILE;
    const int bf = flags[0];

    // stage W2 as f32
    if (bf) {
        for (int i = tid; i < 1024; i += 256) {
            u32 u = W32[i];
            *(float2*)&Wl[2 * i] = make_float2(__uint_as_float(u << 16),
                                               __uint_as_float(u & 0xFFFF0000u));
        }
    } else {
        for (int i = tid; i < 2048; i += 256) Wl[i] = __uint_as_float(W32[i]);
    }
    // stage hin = relu(agg1 + b1), float4-coalesced
    #pragma unroll
    for (int it = 0; it < 8; ++it) {
        int i = tid + it * 256;           // [0, 2048)
        int nl = i >> 4;                  // local node 0..127
        int k  = (i & 15) * 4;
        int n = node0 + nl;
        float4 v = make_float4(0.f, 0.f, 0.f, 0.f);
        if (n < N_NODES) v = *(const float4*)(agg1 + (size_t)n * 64 + k);
        v.x = fmaxf(v.x + ldf(b1, k + 0, bf), 0.f);
        v.y = fmaxf(v.y + ldf(b1, k + 1, bf), 0.f);
        v.z = fmaxf(v.z + ldf(b1, k + 2, bf), 0.f);
        v.w = fmaxf(v.w + ldf(b1, k + 3, bf), 0.f);
        *(float4*)&xs[nl * 68 + k] = v;
    }
    __syncthreads();

    const int ch0 = (tid & 7) * 4;        // 4 output channels
    const int nb0 = (tid >> 3) * 4;       // 4 local nodes
    float acc[4][4];
    #pragma unroll
    for (int j = 0; j < 4; ++j)
        #pragma unroll
        for (int c = 0; c < 4; ++c) acc[j][c] = 0.f;

    #pragma unroll 4
    for (int k0 = 0; k0 < 64; k0 += 4) {
        float4 xv0 = *(const float4*)&xs[(nb0 + 0) * 68 + k0];
        float4 xv1 = *(const float4*)&xs[(nb0 + 1) * 68 + k0];
        float4 xv2 = *(const float4*)&xs[(nb0 + 2) * 68 + k0];
        float4 xv3 = *(const float4*)&xs[(nb0 + 3) * 68 + k0];
        const float* xp[4] = { (const float*)&xv0, (const float*)&xv1,
                               (const float*)&xv2, (const float*)&xv3 };
        #pragma unroll
        for (int kk = 0; kk < 4; ++kk) {
            float4 w = *(const float4*)&Wl[(k0 + kk) * 32 + ch0];
            #pragma unroll
            for (int j = 0; j < 4; ++j) {
                float xvv = xp[j][kk];
                acc[j][0] = fmaf(xvv, w.x, acc[j][0]);
                acc[j][1] = fmaf(xvv, w.y, acc[j][1]);
                acc[j][2] = fmaf(xvv, w.z, acc[j][2]);
                acc[j][3] = fmaf(xvv, w.w, acc[j][3]);
            }
        }
    }

    float av[4], dv[4];
    #pragma unroll
    for (int c = 0; c < 4; ++c) {
        av[c] = ldf(a_src, ch0 + c, bf);
        dv[c] = ldf(a_dst, ch0 + c, bf);
    }
    #pragma unroll
    for (int j = 0; j < 4; ++j) {
        float ps = acc[j][0] * av[0] + acc[j][1] * av[1]
                 + acc[j][2] * av[2] + acc[j][3] * av[3];
        float pd = acc[j][0] * dv[0] + acc[j][1] * dv[1]
                 + acc[j][2] * dv[2] + acc[j][3] * dv[3];
        #pragma unroll
        for (int off = 1; off < 8; off <<= 1) {
            ps += __shfl_xor(ps, off);
            pd += __shfl_xor(pd, off);
        }
        int n = node0 + nb0 + j;
        if (n < N_NODES) {
            u32 p0 = (u32)f2bf(acc[j][0]) | ((u32)f2bf(acc[j][1]) << 16);
            u32 p1 = (u32)f2bf(acc[j][2]) | ((u32)f2bf(acc[j][3]) << 16);
            *(uint2*)&h[(size_t)n * 32 + ch0] = make_uint2(p0, p1);
            if ((tid & 7) == 0) { as_[n] = ps; ad_[n] = pd; }
        }
    }
}

// ---------------------------------------------------------------------------
extern "C" void kernel_launch(void* const* d_in, const int* in_sizes, int n_in,
                              void* d_out, int out_size, void* d_ws, size_t ws_size,
                              hipStream_t stream) {
    const float* x   = (const float*)d_in[0];
    const int* ei    = (const int*)d_in[1];
    const float* W1  = (const float*)d_in[2];
    const void* a_s1 = d_in[3];
    const void* a_d1 = d_in[4];
    const void* b1   = d_in[5];
    const u32* W2    = (const u32*)d_in[6];
    const void* a_s2 = d_in[7];
    const void* a_d2 = d_in[8];
    const void* b2   = d_in[9];
    float* out = (float*)d_out;

    // workspace carve-up (~55 MB)
    char* base = (char*)d_ws;
    int* flags = (int*)base;
    u16* h     = (u16*)(base + 64);                           // N*64 bf16 (reused N*32)
    char* q = base + 64 + (size_t)N_NODES * 64 * 2;
    float* as1 = (float*)q; q += (size_t)N_NODES * 4;
    float* ad1 = (float*)q; q += (size_t)N_NODES * 4;
    float* as2 = (float*)q; q += (size_t)N_NODES * 4;
    float* ad2 = (float*)q; q += (size_t)N_NODES * 4;
    float* agg1 = (float*)q; q += (size_t)N_NODES * 64 * 4;
    u32*  bbuf  = (u32*)q;  q += (size_t)NBUCK * BCAP * 4;    // 8.03 MB
    int* rowptr = (int*)q;  q += (size_t)(N_NODES + 16) * 4;
    int* ssrc   = (int*)q;  q += (size_t)ET * 4;
    int* bcnt   = (int*)q;  q += 256 * 4;
    int* bbase  = (int*)q;  q += 256 * 4;

    detect_kernel<<<1, 64, 0, stream>>>((const u32*)x, ei, flags, bcnt);

    // CSR by dst via 2-pass bucket sort (rowptr built in scatter)
    bin_kernel<<<(ET + BINCH - 1) / BINCH, 256, 0, stream>>>(ei, flags, bcnt, bbuf);
    bscan_kernel<<<1, 256, 0, stream>>>(bcnt, bbase);
    scatter_kernel<<<NBUCK, 1024, 0, stream>>>(bcnt, bbase, bbuf, rowptr, ssrc);

    // layer 1
    gemm1_kernel<<<(N_NODES + 255) / 256, 256, 0, stream>>>(x, W1, a_s1, a_d1, flags, h, as1, ad1);
    gat_agg64_kernel<<<(N_NODES + 3) / 4, 256, 0, stream>>>(rowptr, ssrc, as1, ad1, h, agg1);

    // layer 2 (lsm fused; writes d_out directly)
    gemm2_kernel<<<(N_NODES + G2_TILE - 1) / G2_TILE, 256, 0, stream>>>(agg1, b1, W2, a_s2, a_d2, flags, h, as2, ad2);
    gat_agg32_lsm_kernel<<<(N_NODES + 3) / 4, 256, 0, stream>>>(rowptr, ssrc, as2, ad2, h, b2, flags, out);
}